// Round 5
// baseline (1601.671 us; speedup 1.0000x reference)
//
#include <hip/hip_runtime.h>
#include <stdint.h>

typedef float f32x4 __attribute__((ext_vector_type(4)));
typedef short bf16x8 __attribute__((ext_vector_type(8)));

#define TANH_C 2.885390081777927f   // 2*log2(e)

// pack {odd[31:16] : even[31:16]} -> one u32 of two bf16 (even in low half)
__device__ __forceinline__ uint32_t prm_hi(uint32_t odd, uint32_t even) {
  return __builtin_amdgcn_perm(odd, even, 0x07060302u);
}
__device__ __forceinline__ float rcp_fast(float d) {
  float r; asm("v_rcp_f32 %0, %1" : "=v"(r) : "v"(d)); return r;
}
__device__ __forceinline__ float exp2_fast(float x) {
  float r; asm("v_exp_f32 %0, %1" : "=v"(r) : "v"(x)); return r;
}
__device__ __forceinline__ f32x4 mfma16(bf16x8 a, bf16x8 b, f32x4 c) {
  return __builtin_amdgcn_mfma_f32_16x16x32_bf16(a, b, c, 0, 0, 0);
}
__device__ __forceinline__ bf16x8 bc(uint4 v) { return __builtin_bit_cast(bf16x8, v); }

// ---- hi/lo split pack (Y state): trunc hi + residual lo ----
// Slot convention: frag kk, word w, half h <-> k = 16*(2kk+(w>>1)) + 4g + 2*(w&1) + h
__device__ __forceinline__ void pack16(const float v[4][4], uint4 H[2], uint4 L[2]) {
  uint32_t hw[8], lw[8];
  #pragma unroll
  for (int kk = 0; kk < 2; ++kk)
    #pragma unroll
    for (int w = 0; w < 4; ++w) {
      int mt = 2 * kk + (w >> 1), ie = 2 * (w & 1);
      float ve = v[mt][ie], vo = v[mt][ie + 1];
      uint32_t ue = __float_as_uint(ve), uo = __float_as_uint(vo);
      float he = __uint_as_float(ue & 0xFFFF0000u);
      float ho = __uint_as_float(uo & 0xFFFF0000u);
      hw[kk * 4 + w] = prm_hi(uo, ue);
      lw[kk * 4 + w] = prm_hi(__float_as_uint(vo - ho), __float_as_uint(ve - he));
    }
  H[0] = (uint4){hw[0], hw[1], hw[2], hw[3]};
  H[1] = (uint4){hw[4], hw[5], hw[6], hw[7]};
  L[0] = (uint4){lw[0], lw[1], lw[2], lw[3]};
  L[1] = (uint4){lw[4], lw[5], lw[6], lw[7]};
}

// ---- single-bf16 RNE pack (T states) ----
__device__ __forceinline__ void pack16h(const float v[4][4], uint4 H[2]) {
  uint32_t hw[8];
  #pragma unroll
  for (int kk = 0; kk < 2; ++kk)
    #pragma unroll
    for (int w = 0; w < 4; ++w) {
      int mt = 2 * kk + (w >> 1), ie = 2 * (w & 1);
      uint32_t r;
      asm("v_cvt_pk_bf16_f32 %0, %1, %2" : "=v"(r) : "v"(v[mt][ie]), "v"(v[mt][ie + 1]));
      hw[kk * 4 + w] = r;
    }
  H[0] = (uint4){hw[0], hw[1], hw[2], hw[3]};
  H[1] = (uint4){hw[4], hw[5], hw[6], hw[7]};
}

// butterfly reduce across the four 16-lane groups
__device__ __forceinline__ float xreduce(float v) {
  int t = __builtin_amdgcn_ds_swizzle(__float_as_int(v), 0x401F); // lane ^= 16
  v += __int_as_float(t);
  float a = v, b = v;
  asm volatile("v_permlane32_swap_b32 %0, %1" : "+v"(a), "+v"(b));
  return a + b;   // lane i: v[i] + v[i^32]
}

// Pre-split A = W^T into hi/lo bf16 A-frags. Frag f = (l*4+mt)*2+kk.
// Lane (r=lane&15, g=lane>>4): row_out = 16mt+r; slot (w,h) holds
// W^T[row_out][k] = Ws[l][k][row_out], k = 16*(2kk+(w>>1)) + 4g + 2*(w&1) + h.
__global__ void __launch_bounds__(64) prep_kernel(const float* __restrict__ Ws,
                                                  uint4* __restrict__ whi,
                                                  uint4* __restrict__ wlo) {
  int f = blockIdx.x, lane = threadIdx.x;
  int kk = f & 1, mt = (f >> 1) & 3, l = f >> 3;
  int r = lane & 15, g = lane >> 4;
  uint32_t hw[4], lw[4];
  #pragma unroll
  for (int w = 0; w < 4; ++w) {
    uint32_t uu[2], res[2];
    #pragma unroll
    for (int h = 0; h < 2; ++h) {
      int k = 16 * (2 * kk + (w >> 1)) + 4 * g + 2 * (w & 1) + h;
      float v = Ws[l * 4096 + k * 64 + 16 * mt + r];
      uu[h] = __float_as_uint(v);
      res[h] = __float_as_uint(v - __uint_as_float(uu[h] & 0xFFFF0000u));
    }
    hw[w] = prm_hi(uu[1], uu[0]);
    lw[w] = prm_hi(res[1], res[0]);
  }
  whi[f * 64 + lane] = (uint4){hw[0], hw[1], hw[2], hw[3]};
  wlo[f * 64 + lane] = (uint4){lw[0], lw[1], lw[2], lw[3]};
}

// 4 independent waves per 256-thread block; each wave owns 16 points (p = lane&15).
// State transposed (X^T) in MFMA C-layout; repack to B-frags is in-lane, zero LDS.
// Y: hi/lo 3-term MFMA; T0/T1: single RNE bf16, 2-term.
__global__ void __launch_bounds__(256, 8) velprevec_kernel(
    const float* __restrict__ x, const float* __restrict__ Win,
    const float* __restrict__ bin, const float* __restrict__ bs,
    const float* __restrict__ Wout, const uint4* __restrict__ whi,
    const uint4* __restrict__ wlo, float* __restrict__ out) {
  const int lane = threadIdx.x & 63;
  const int wid  = threadIdx.x >> 6;
  const int p0 = (blockIdx.x * 4 + wid) * 16;
  const int p = lane & 15, g = lane >> 4;
  const int fb = 4 * g;

  // ---- layer 0: Y = x@Win + bin; T0 = Win row0, T1 = Win row1 ----
  const float* xp = &x[(p0 + p) * 3];
  float x0 = xp[0], x1 = xp[1], x2 = xp[2];

  uint4 BYh[2], BYl[2], B0h[2], B1h[2];
  {
    float Yv[4][4], T0v[4][4], T1v[4][4];
    #pragma unroll
    for (int mt = 0; mt < 4; ++mt) {
      f32x4 w0 = *(const f32x4*)&Win[      16 * mt + fb];
      f32x4 w1 = *(const f32x4*)&Win[ 64 + 16 * mt + fb];
      f32x4 w2 = *(const f32x4*)&Win[128 + 16 * mt + fb];
      f32x4 bb = *(const f32x4*)&bin[      16 * mt + fb];
      #pragma unroll
      for (int i = 0; i < 4; ++i) {
        Yv[mt][i]  = fmaf(x0, w0[i], fmaf(x1, w1[i], fmaf(x2, w2[i], bb[i])));
        T0v[mt][i] = w0[i];
        T1v[mt][i] = w1[i];
      }
    }
    pack16(Yv, BYh, BYl);
    pack16h(T0v, B0h);
    pack16h(T1v, B1h);
  }

  float T0n[4][4], T1n[4][4];

  // ---- 7 hidden layers, zero LDS ----
  #pragma unroll 1
  for (int l = 0; l < 7; ++l) {
    const uint4* ph  = whi + l * 8 * 64 + lane;
    const uint4* pl_ = wlo + l * 8 * 64 + lane;
    f32x4 aY[4], a0[4], a1[4];
    #pragma unroll
    for (int mt = 0; mt < 4; ++mt) {
      aY[mt] = *(const f32x4*)&bs[l * 64 + 16 * mt + fb];   // bias pre-loaded into acc
      a0[mt] = (f32x4){0.f, 0.f, 0.f, 0.f};
      a1[mt] = (f32x4){0.f, 0.f, 0.f, 0.f};
    }
    #pragma unroll
    for (int kk = 0; kk < 2; ++kk) {
      uint4 Ah[4], Al[4];
      #pragma unroll
      for (int mt = 0; mt < 4; ++mt) {
        Ah[mt] = ph[(mt * 2 + kk) * 64];
        Al[mt] = pl_[(mt * 2 + kk) * 64];
      }
      bf16x8 bYh = bc(BYh[kk]), bYl = bc(BYl[kk]);
      bf16x8 b0 = bc(B0h[kk]), b1 = bc(B1h[kk]);
      #pragma unroll
      for (int mt = 0; mt < 4; ++mt) aY[mt] = mfma16(bc(Ah[mt]), bYh, aY[mt]);
      #pragma unroll
      for (int mt = 0; mt < 4; ++mt) a0[mt] = mfma16(bc(Ah[mt]), b0, a0[mt]);
      #pragma unroll
      for (int mt = 0; mt < 4; ++mt) a1[mt] = mfma16(bc(Ah[mt]), b1, a1[mt]);
      #pragma unroll
      for (int mt = 0; mt < 4; ++mt) aY[mt] = mfma16(bc(Ah[mt]), bYl, aY[mt]);
      #pragma unroll
      for (int mt = 0; mt < 4; ++mt) aY[mt] = mfma16(bc(Al[mt]), bYh, aY[mt]);
      #pragma unroll
      for (int mt = 0; mt < 4; ++mt) a0[mt] = mfma16(bc(Al[mt]), b0, a0[mt]);
      #pragma unroll
      for (int mt = 0; mt < 4; ++mt) a1[mt] = mfma16(bc(Al[mt]), b1, a1[mt]);
    }
    // epilogue: tanh + tangent scale, all in-register
    float Yn[4][4];
    #pragma unroll
    for (int mt = 0; mt < 4; ++mt) {
      #pragma unroll
      for (int i = 0; i < 4; ++i) {
        float e = exp2_fast(aY[mt][i] * TANH_C);
        float r = rcp_fast(e + 1.f);
        float t = fmaf(-2.f, r, 1.f);     // tanh(z)
        float s = fmaf(-t, t, 1.f);       // sech^2(z)
        Yn[mt][i]  = t;
        T0n[mt][i] = s * a0[mt][i];
        T1n[mt][i] = s * a1[mt][i];
      }
    }
    if (l < 6) {
      pack16(Yn, BYh, BYl);
      pack16h(T0n, B0h);
      pack16h(T1n, B1h);
    }
  }

  // ---- output: J_{jo} = T_j . Wout[:,o];  u = [J10, -J00, J01, J11] ----
  float J00 = 0.f, J01 = 0.f, J10 = 0.f, J11 = 0.f;
  #pragma unroll
  for (int mt = 0; mt < 4; ++mt) {
    f32x4 wa = *(const f32x4*)&Wout[(16 * mt + fb) * 2];      // feats f0,f1: (W0,W1,W0,W1)
    f32x4 wb = *(const f32x4*)&Wout[(16 * mt + fb) * 2 + 4];  // feats f2,f3
    J00 = fmaf(T0n[mt][0], wa[0], fmaf(T0n[mt][1], wa[2], fmaf(T0n[mt][2], wb[0], fmaf(T0n[mt][3], wb[2], J00))));
    J01 = fmaf(T0n[mt][0], wa[1], fmaf(T0n[mt][1], wa[3], fmaf(T0n[mt][2], wb[1], fmaf(T0n[mt][3], wb[3], J01))));
    J10 = fmaf(T1n[mt][0], wa[0], fmaf(T1n[mt][1], wa[2], fmaf(T1n[mt][2], wb[0], fmaf(T1n[mt][3], wb[2], J10))));
    J11 = fmaf(T1n[mt][0], wa[1], fmaf(T1n[mt][1], wa[3], fmaf(T1n[mt][2], wb[1], fmaf(T1n[mt][3], wb[3], J11))));
  }
  J00 = xreduce(J00); J01 = xreduce(J01); J10 = xreduce(J10); J11 = xreduce(J11);
  float val = (g == 0) ? J10 : (g == 1) ? -J00 : (g == 2) ? J01 : J11;
  out[(p0 + p) * 4 + g] = val;
}

extern "C" void kernel_launch(void* const* d_in, const int* in_sizes, int n_in,
                              void* d_out, int out_size, void* d_ws, size_t ws_size,
                              hipStream_t stream) {
  const float* x    = (const float*)d_in[0];
  const float* Win  = (const float*)d_in[1];
  const float* bin  = (const float*)d_in[2];
  const float* Ws   = (const float*)d_in[3];
  const float* bs   = (const float*)d_in[4];
  const float* Wout = (const float*)d_in[5];
  float* out = (float*)d_out;

  uint4* whi = (uint4*)d_ws;
  uint4* wlo = whi + 56 * 64;

  int N = in_sizes[0] / 3;      // 524288

  prep_kernel<<<56, 64, 0, stream>>>(Ws, whi, wlo);
  velprevec_kernel<<<N / 64, 256, 0, stream>>>(x, Win, bin, bs, Wout, whi, wlo, out);
}

// Round 6
// 798.442 us; speedup vs baseline: 2.0060x; 2.0060x over previous
//
#include <hip/hip_runtime.h>
#include <stdint.h>

typedef float f32x4 __attribute__((ext_vector_type(4)));
typedef short bf16x8 __attribute__((ext_vector_type(8)));

#define TANH_C 2.885390081777927f   // 2*log2(e)

// pack {odd[31:16] : even[31:16]} -> one u32 of two bf16 (even in low half)
__device__ __forceinline__ uint32_t prm_hi(uint32_t odd, uint32_t even) {
  return __builtin_amdgcn_perm(odd, even, 0x07060302u);
}
__device__ __forceinline__ float rcp_fast(float d) {
  float r; asm("v_rcp_f32 %0, %1" : "=v"(r) : "v"(d)); return r;
}
__device__ __forceinline__ float exp2_fast(float x) {
  float r; asm("v_exp_f32 %0, %1" : "=v"(r) : "v"(x)); return r;
}
__device__ __forceinline__ f32x4 mfma16(bf16x8 a, bf16x8 b, f32x4 c) {
  return __builtin_amdgcn_mfma_f32_16x16x32_bf16(a, b, c, 0, 0, 0);
}
__device__ __forceinline__ bf16x8 bc(uint4 v) { return __builtin_bit_cast(bf16x8, v); }

// ---- hi/lo split pack (Y state): trunc hi + residual lo ----
// Slot convention: frag kk, word w, half h <-> k = 16*(2kk+(w>>1)) + 4g + 2*(w&1) + h
__device__ __forceinline__ void pack16(const float v[4][4], uint4 H[2], uint4 L[2]) {
  uint32_t hw[8], lw[8];
  #pragma unroll
  for (int kk = 0; kk < 2; ++kk)
    #pragma unroll
    for (int w = 0; w < 4; ++w) {
      int mt = 2 * kk + (w >> 1), ie = 2 * (w & 1);
      float ve = v[mt][ie], vo = v[mt][ie + 1];
      uint32_t ue = __float_as_uint(ve), uo = __float_as_uint(vo);
      float he = __uint_as_float(ue & 0xFFFF0000u);
      float ho = __uint_as_float(uo & 0xFFFF0000u);
      hw[kk * 4 + w] = prm_hi(uo, ue);
      lw[kk * 4 + w] = prm_hi(__float_as_uint(vo - ho), __float_as_uint(ve - he));
    }
  H[0] = (uint4){hw[0], hw[1], hw[2], hw[3]};
  H[1] = (uint4){hw[4], hw[5], hw[6], hw[7]};
  L[0] = (uint4){lw[0], lw[1], lw[2], lw[3]};
  L[1] = (uint4){lw[4], lw[5], lw[6], lw[7]};
}

// ---- single-bf16 RNE pack (T states) ----
__device__ __forceinline__ void pack16h(const float v[4][4], uint4 H[2]) {
  uint32_t hw[8];
  #pragma unroll
  for (int kk = 0; kk < 2; ++kk)
    #pragma unroll
    for (int w = 0; w < 4; ++w) {
      int mt = 2 * kk + (w >> 1), ie = 2 * (w & 1);
      uint32_t r;
      asm("v_cvt_pk_bf16_f32 %0, %1, %2" : "=v"(r) : "v"(v[mt][ie]), "v"(v[mt][ie + 1]));
      hw[kk * 4 + w] = r;
    }
  H[0] = (uint4){hw[0], hw[1], hw[2], hw[3]};
  H[1] = (uint4){hw[4], hw[5], hw[6], hw[7]};
}

// butterfly reduce across the four 16-lane groups
__device__ __forceinline__ float xreduce(float v) {
  int t = __builtin_amdgcn_ds_swizzle(__float_as_int(v), 0x401F); // lane ^= 16
  v += __int_as_float(t);
  float a = v, b = v;
  asm volatile("v_permlane32_swap_b32 %0, %1" : "+v"(a), "+v"(b));
  return a + b;   // lane i: v[i] + v[i^32]
}

// Pre-split A = W^T into hi/lo bf16 A-frags. Frag f = (l*4+mt)*2+kk.
// Lane (r=lane&15, g=lane>>4): row_out = 16mt+r; slot (w,h) holds
// W^T[row_out][k] = Ws[l][k][row_out], k = 16*(2kk+(w>>1)) + 4g + 2*(w&1) + h.
__global__ void __launch_bounds__(64) prep_kernel(const float* __restrict__ Ws,
                                                  uint4* __restrict__ whi,
                                                  uint4* __restrict__ wlo) {
  int f = blockIdx.x, lane = threadIdx.x;
  int kk = f & 1, mt = (f >> 1) & 3, l = f >> 3;
  int r = lane & 15, g = lane >> 4;
  uint32_t hw[4], lw[4];
  #pragma unroll
  for (int w = 0; w < 4; ++w) {
    uint32_t uu[2], res[2];
    #pragma unroll
    for (int h = 0; h < 2; ++h) {
      int k = 16 * (2 * kk + (w >> 1)) + 4 * g + 2 * (w & 1) + h;
      float v = Ws[l * 4096 + k * 64 + 16 * mt + r];
      uu[h] = __float_as_uint(v);
      res[h] = __float_as_uint(v - __uint_as_float(uu[h] & 0xFFFF0000u));
    }
    hw[w] = prm_hi(uu[1], uu[0]);
    lw[w] = prm_hi(res[1], res[0]);
  }
  whi[f * 64 + lane] = (uint4){hw[0], hw[1], hw[2], hw[3]};
  wlo[f * 64 + lane] = (uint4){lw[0], lw[1], lw[2], lw[3]};
}

// 4 independent waves per 256-thread block; each wave owns 16 points (p = lane&15).
// State transposed (X^T) in MFMA C-layout; repack to B-frags is in-lane, zero LDS.
// Register-lean: 3 sequential accumulation passes per layer (Y 3-term, T0, T1),
// A-frags reloaded per pass (L1/L2-resident weights).
__global__ void __launch_bounds__(256, 5) velprevec_kernel(
    const float* __restrict__ x, const float* __restrict__ Win,
    const float* __restrict__ bin, const float* __restrict__ bs,
    const float* __restrict__ Wout, const uint4* __restrict__ whi,
    const uint4* __restrict__ wlo, float* __restrict__ out) {
  const int lane = threadIdx.x & 63;
  const int wid  = threadIdx.x >> 6;
  const int p0 = (blockIdx.x * 4 + wid) * 16;
  const int p = lane & 15, g = lane >> 4;
  const int fb = 4 * g;

  // ---- layer 0: Y = x@Win + bin; T0 = Win row0, T1 = Win row1 ----
  const float* xp = &x[(p0 + p) * 3];
  float x0 = xp[0], x1 = xp[1], x2 = xp[2];

  uint4 BYh[2], BYl[2], B0h[2], B1h[2];
  {
    float Yv[4][4], T0v[4][4], T1v[4][4];
    #pragma unroll
    for (int mt = 0; mt < 4; ++mt) {
      f32x4 w0 = *(const f32x4*)&Win[      16 * mt + fb];
      f32x4 w1 = *(const f32x4*)&Win[ 64 + 16 * mt + fb];
      f32x4 w2 = *(const f32x4*)&Win[128 + 16 * mt + fb];
      f32x4 bb = *(const f32x4*)&bin[      16 * mt + fb];
      #pragma unroll
      for (int i = 0; i < 4; ++i) {
        Yv[mt][i]  = fmaf(x0, w0[i], fmaf(x1, w1[i], fmaf(x2, w2[i], bb[i])));
        T0v[mt][i] = w0[i];
        T1v[mt][i] = w1[i];
      }
    }
    pack16(Yv, BYh, BYl);
    pack16h(T0v, B0h);
    pack16h(T1v, B1h);
  }

  float T0n[4][4], T1n[4][4];

  // ---- 7 hidden layers, zero LDS ----
  #pragma unroll 1
  for (int l = 0; l < 7; ++l) {
    const uint4* ph  = whi + l * 512 + lane;
    const uint4* pl_ = wlo + l * 512 + lane;

    // ---- Y pass (3-term split) ----
    f32x4 aY[4];
    #pragma unroll
    for (int mt = 0; mt < 4; ++mt)
      aY[mt] = *(const f32x4*)&bs[l * 64 + 16 * mt + fb];   // bias in acc
    #pragma unroll
    for (int kk = 0; kk < 2; ++kk) {
      bf16x8 bYh = bc(BYh[kk]), bYl = bc(BYl[kk]);
      #pragma unroll
      for (int mt = 0; mt < 4; ++mt) {
        uint4 Ah = ph[(mt * 2 + kk) * 64];
        uint4 Al = pl_[(mt * 2 + kk) * 64];
        aY[mt] = mfma16(bc(Ah), bYh, aY[mt]);
        aY[mt] = mfma16(bc(Ah), bYl, aY[mt]);
        aY[mt] = mfma16(bc(Al), bYh, aY[mt]);
      }
    }
    float s[4][4];
    {
      float Yn[4][4];
      #pragma unroll
      for (int mt = 0; mt < 4; ++mt)
        #pragma unroll
        for (int i = 0; i < 4; ++i) {
          float e = exp2_fast(aY[mt][i] * TANH_C);
          float r = rcp_fast(e + 1.f);
          float t = fmaf(-2.f, r, 1.f);     // tanh(z)
          s[mt][i] = fmaf(-t, t, 1.f);      // sech^2(z)
          Yn[mt][i] = t;
        }
      if (l < 6) pack16(Yn, BYh, BYl);
    }

    // ---- T0 pass (single-bf16) ----
    {
      f32x4 a0[4];
      #pragma unroll
      for (int mt = 0; mt < 4; ++mt) a0[mt] = (f32x4){0.f, 0.f, 0.f, 0.f};
      #pragma unroll
      for (int kk = 0; kk < 2; ++kk) {
        bf16x8 b0 = bc(B0h[kk]);
        #pragma unroll
        for (int mt = 0; mt < 4; ++mt) {
          uint4 Ah = ph[(mt * 2 + kk) * 64];
          uint4 Al = pl_[(mt * 2 + kk) * 64];
          a0[mt] = mfma16(bc(Ah), b0, a0[mt]);
          a0[mt] = mfma16(bc(Al), b0, a0[mt]);
        }
      }
      #pragma unroll
      for (int mt = 0; mt < 4; ++mt)
        #pragma unroll
        for (int i = 0; i < 4; ++i) T0n[mt][i] = s[mt][i] * a0[mt][i];
      if (l < 6) pack16h(T0n, B0h);
    }

    // ---- T1 pass (single-bf16) ----
    {
      f32x4 a1[4];
      #pragma unroll
      for (int mt = 0; mt < 4; ++mt) a1[mt] = (f32x4){0.f, 0.f, 0.f, 0.f};
      #pragma unroll
      for (int kk = 0; kk < 2; ++kk) {
        bf16x8 b1 = bc(B1h[kk]);
        #pragma unroll
        for (int mt = 0; mt < 4; ++mt) {
          uint4 Ah = ph[(mt * 2 + kk) * 64];
          uint4 Al = pl_[(mt * 2 + kk) * 64];
          a1[mt] = mfma16(bc(Ah), b1, a1[mt]);
          a1[mt] = mfma16(bc(Al), b1, a1[mt]);
        }
      }
      #pragma unroll
      for (int mt = 0; mt < 4; ++mt)
        #pragma unroll
        for (int i = 0; i < 4; ++i) T1n[mt][i] = s[mt][i] * a1[mt][i];
      if (l < 6) pack16h(T1n, B1h);
    }
  }

  // ---- output: J_{jo} = T_j . Wout[:,o];  u = [J10, -J00, J01, J11] ----
  float J00 = 0.f, J01 = 0.f, J10 = 0.f, J11 = 0.f;
  #pragma unroll
  for (int mt = 0; mt < 4; ++mt) {
    f32x4 wa = *(const f32x4*)&Wout[(16 * mt + fb) * 2];      // feats f0,f1: (W0,W1,W0,W1)
    f32x4 wb = *(const f32x4*)&Wout[(16 * mt + fb) * 2 + 4];  // feats f2,f3
    J00 = fmaf(T0n[mt][0], wa[0], fmaf(T0n[mt][1], wa[2], fmaf(T0n[mt][2], wb[0], fmaf(T0n[mt][3], wb[2], J00))));
    J01 = fmaf(T0n[mt][0], wa[1], fmaf(T0n[mt][1], wa[3], fmaf(T0n[mt][2], wb[1], fmaf(T0n[mt][3], wb[3], J01))));
    J10 = fmaf(T1n[mt][0], wa[0], fmaf(T1n[mt][1], wa[2], fmaf(T1n[mt][2], wb[0], fmaf(T1n[mt][3], wb[2], J10))));
    J11 = fmaf(T1n[mt][0], wa[1], fmaf(T1n[mt][1], wa[3], fmaf(T1n[mt][2], wb[1], fmaf(T1n[mt][3], wb[3], J11))));
  }
  J00 = xreduce(J00); J01 = xreduce(J01); J10 = xreduce(J10); J11 = xreduce(J11);
  float val = (g == 0) ? J10 : (g == 1) ? -J00 : (g == 2) ? J01 : J11;
  out[(p0 + p) * 4 + g] = val;
}

extern "C" void kernel_launch(void* const* d_in, const int* in_sizes, int n_in,
                              void* d_out, int out_size, void* d_ws, size_t ws_size,
                              hipStream_t stream) {
  const float* x    = (const float*)d_in[0];
  const float* Win  = (const float*)d_in[1];
  const float* bin  = (const float*)d_in[2];
  const float* Ws   = (const float*)d_in[3];
  const float* bs   = (const float*)d_in[4];
  const float* Wout = (const float*)d_in[5];
  float* out = (float*)d_out;

  uint4* whi = (uint4*)d_ws;
  uint4* wlo = whi + 56 * 64;

  int N = in_sizes[0] / 3;      // 524288

  prep_kernel<<<56, 64, 0, stream>>>(Ws, whi, wlo);
  velprevec_kernel<<<N / 64, 256, 0, stream>>>(x, Win, bin, bs, Wout, whi, wlo, out);
}

// Round 7
// 595.679 us; speedup vs baseline: 2.6888x; 1.3404x over previous
//
#include <hip/hip_runtime.h>
#include <stdint.h>

typedef float f32x4 __attribute__((ext_vector_type(4)));
typedef short bf16x8 __attribute__((ext_vector_type(8)));

#define TANH_C 2.885390081777927f   // 2*log2(e)

// pack {odd[31:16] : even[31:16]} -> one u32 of two bf16 (even in low half)
__device__ __forceinline__ uint32_t prm_hi(uint32_t odd, uint32_t even) {
  return __builtin_amdgcn_perm(odd, even, 0x07060302u);
}
__device__ __forceinline__ float rcp_fast(float d) {
  float r; asm("v_rcp_f32 %0, %1" : "=v"(r) : "v"(d)); return r;
}
__device__ __forceinline__ float exp2_fast(float x) {
  float r; asm("v_exp_f32 %0, %1" : "=v"(r) : "v"(x)); return r;
}
__device__ __forceinline__ f32x4 mfma16(bf16x8 a, bf16x8 b, f32x4 c) {
  return __builtin_amdgcn_mfma_f32_16x16x32_bf16(a, b, c, 0, 0, 0);
}
__device__ __forceinline__ bf16x8 bc(uint4 v) { return __builtin_bit_cast(bf16x8, v); }

// ---- hi/lo split pack (Y state) into LDS slots ----
// Slot convention: frag kk, word w, half h <-> k = 16*(2kk+(w>>1)) + 4g + 2*(w&1) + h
__device__ __forceinline__ void pack16_lds(const float v[4][4], uint4* H, uint4* L) {
  #pragma unroll
  for (int kk = 0; kk < 2; ++kk) {
    uint32_t hw[4], lw[4];
    #pragma unroll
    for (int w = 0; w < 4; ++w) {
      int mt = 2 * kk + (w >> 1), ie = 2 * (w & 1);
      float ve = v[mt][ie], vo = v[mt][ie + 1];
      uint32_t ue = __float_as_uint(ve), uo = __float_as_uint(vo);
      float he = __uint_as_float(ue & 0xFFFF0000u);
      float ho = __uint_as_float(uo & 0xFFFF0000u);
      hw[w] = prm_hi(uo, ue);
      lw[w] = prm_hi(__float_as_uint(vo - ho), __float_as_uint(ve - he));
    }
    H[kk * 64] = (uint4){hw[0], hw[1], hw[2], hw[3]};
    L[kk * 64] = (uint4){lw[0], lw[1], lw[2], lw[3]};
  }
}

// ---- single-bf16 RNE pack (T states) into LDS slots ----
__device__ __forceinline__ void pack16h_lds(const float v[4][4], uint4* H) {
  #pragma unroll
  for (int kk = 0; kk < 2; ++kk) {
    uint32_t hw[4];
    #pragma unroll
    for (int w = 0; w < 4; ++w) {
      int mt = 2 * kk + (w >> 1), ie = 2 * (w & 1);
      uint32_t r;
      asm("v_cvt_pk_bf16_f32 %0, %1, %2" : "=v"(r) : "v"(v[mt][ie]), "v"(v[mt][ie + 1]));
      hw[w] = r;
    }
    H[kk * 64] = (uint4){hw[0], hw[1], hw[2], hw[3]};
  }
}

// butterfly reduce across the four 16-lane groups
__device__ __forceinline__ float xreduce(float v) {
  int t = __builtin_amdgcn_ds_swizzle(__float_as_int(v), 0x401F); // lane ^= 16
  v += __int_as_float(t);
  float a = v, b = v;
  asm volatile("v_permlane32_swap_b32 %0, %1" : "+v"(a), "+v"(b));
  return a + b;   // lane i: v[i] + v[i^32]
}

// Pre-split A = W^T into hi/lo bf16 A-frags. Frag f = (l*4+mt)*2+kk.
// Lane (r=lane&15, g=lane>>4): row_out = 16mt+r; slot (w,h) holds
// W^T[row_out][k] = Ws[l][k][row_out], k = 16*(2kk+(w>>1)) + 4g + 2*(w&1) + h.
__global__ void __launch_bounds__(64) prep_kernel(const float* __restrict__ Ws,
                                                  uint4* __restrict__ whi,
                                                  uint4* __restrict__ wlo) {
  int f = blockIdx.x, lane = threadIdx.x;
  int kk = f & 1, mt = (f >> 1) & 3, l = f >> 3;
  int r = lane & 15, g = lane >> 4;
  uint32_t hw[4], lw[4];
  #pragma unroll
  for (int w = 0; w < 4; ++w) {
    uint32_t uu[2], res[2];
    #pragma unroll
    for (int h = 0; h < 2; ++h) {
      int k = 16 * (2 * kk + (w >> 1)) + 4 * g + 2 * (w & 1) + h;
      float v = Ws[l * 4096 + k * 64 + 16 * mt + r];
      uu[h] = __float_as_uint(v);
      res[h] = __float_as_uint(v - __uint_as_float(uu[h] & 0xFFFF0000u));
    }
    hw[w] = prm_hi(uu[1], uu[0]);
    lw[w] = prm_hi(res[1], res[0]);
  }
  whi[f * 64 + lane] = (uint4){hw[0], hw[1], hw[2], hw[3]};
  wlo[f * 64 + lane] = (uint4){lw[0], lw[1], lw[2], lw[3]};
}

// 4 waves/block, 16 points per wave (p = lane&15). State transposed (X^T) in MFMA
// C-layout; repack to B-frags is in-lane. Persistent B-frags live in LANE-PRIVATE
// LDS slots (no barriers needed) to relieve register pressure. Two half-passes per
// layer: pass A = Y (3-term hi/lo), pass B = T0+T1 (single bf16); A-frags reloaded
// from L1 per pass.
// LDS frag slots per wave: 0,1 = BYh(kk=0,1); 2,3 = BYl; 4,5 = B0h; 6,7 = B1h.
__global__ void __launch_bounds__(256, 5) velprevec_kernel(
    const float* __restrict__ x, const float* __restrict__ Win,
    const float* __restrict__ bin, const float* __restrict__ bs,
    const float* __restrict__ Wout, const uint4* __restrict__ whi,
    const uint4* __restrict__ wlo, float* __restrict__ out) {
  __shared__ uint4 bfr[4][8][64];
  const int lane = threadIdx.x & 63;
  const int wid  = threadIdx.x >> 6;
  const int p0 = (blockIdx.x * 4 + wid) * 16;
  const int p = lane & 15, g = lane >> 4;
  const int fb = 4 * g;

  uint4* BY_h = &bfr[wid][0][lane];   // [kk*64]
  uint4* BY_l = &bfr[wid][2][lane];
  uint4* B0_h = &bfr[wid][4][lane];
  uint4* B1_h = &bfr[wid][6][lane];

  // ---- layer 0: Y = x@Win + bin; T0 = Win row0, T1 = Win row1 ----
  const float* xp = &x[(p0 + p) * 3];
  float x0 = xp[0], x1 = xp[1], x2 = xp[2];
  {
    float Yv[4][4], T0v[4][4], T1v[4][4];
    #pragma unroll
    for (int mt = 0; mt < 4; ++mt) {
      f32x4 w0 = *(const f32x4*)&Win[      16 * mt + fb];
      f32x4 w1 = *(const f32x4*)&Win[ 64 + 16 * mt + fb];
      f32x4 w2 = *(const f32x4*)&Win[128 + 16 * mt + fb];
      f32x4 bb = *(const f32x4*)&bin[      16 * mt + fb];
      #pragma unroll
      for (int i = 0; i < 4; ++i) {
        Yv[mt][i]  = fmaf(x0, w0[i], fmaf(x1, w1[i], fmaf(x2, w2[i], bb[i])));
        T0v[mt][i] = w0[i];
        T1v[mt][i] = w1[i];
      }
    }
    pack16_lds(Yv, BY_h, BY_l);
    pack16h_lds(T0v, B0_h);
    pack16h_lds(T1v, B1_h);
  }

  float T0n[4][4], T1n[4][4];

  // ---- 7 hidden layers ----
  #pragma unroll 1
  for (int l = 0; l < 7; ++l) {
    const uint4* ph  = whi + l * 512 + lane;
    const uint4* pl_ = wlo + l * 512 + lane;

    // ===== pass A: Y (3-term hi/lo split) =====
    f32x4 aY[4];
    #pragma unroll
    for (int mt = 0; mt < 4; ++mt)
      aY[mt] = *(const f32x4*)&bs[l * 64 + 16 * mt + fb];   // bias in acc
    #pragma unroll
    for (int kk = 0; kk < 2; ++kk) {
      uint4 Ah[4], Al[4];
      #pragma unroll
      for (int mt = 0; mt < 4; ++mt) {
        Ah[mt] = ph[(mt * 2 + kk) * 64];
        Al[mt] = pl_[(mt * 2 + kk) * 64];
      }
      bf16x8 bYh = bc(BY_h[kk * 64]), bYl = bc(BY_l[kk * 64]);
      #pragma unroll
      for (int mt = 0; mt < 4; ++mt) aY[mt] = mfma16(bc(Ah[mt]), bYh, aY[mt]);
      #pragma unroll
      for (int mt = 0; mt < 4; ++mt) aY[mt] = mfma16(bc(Ah[mt]), bYl, aY[mt]);
      #pragma unroll
      for (int mt = 0; mt < 4; ++mt) aY[mt] = mfma16(bc(Al[mt]), bYh, aY[mt]);
    }
    float s[4][4];
    {
      float Yn[4][4];
      #pragma unroll
      for (int mt = 0; mt < 4; ++mt)
        #pragma unroll
        for (int i = 0; i < 4; ++i) {
          float e = exp2_fast(aY[mt][i] * TANH_C);
          float r = rcp_fast(e + 1.f);
          float t = fmaf(-2.f, r, 1.f);     // tanh(z)
          s[mt][i] = fmaf(-t, t, 1.f);      // sech^2(z)
          Yn[mt][i] = t;
        }
      if (l < 6) pack16_lds(Yn, BY_h, BY_l);
    }

    // ===== pass B: T0 + T1 (single bf16, 2-term A hi/lo) =====
    f32x4 a0[4], a1[4];
    #pragma unroll
    for (int mt = 0; mt < 4; ++mt) {
      a0[mt] = (f32x4){0.f, 0.f, 0.f, 0.f};
      a1[mt] = (f32x4){0.f, 0.f, 0.f, 0.f};
    }
    #pragma unroll
    for (int kk = 0; kk < 2; ++kk) {
      uint4 Ah[4], Al[4];
      #pragma unroll
      for (int mt = 0; mt < 4; ++mt) {
        Ah[mt] = ph[(mt * 2 + kk) * 64];
        Al[mt] = pl_[(mt * 2 + kk) * 64];
      }
      bf16x8 b0 = bc(B0_h[kk * 64]), b1 = bc(B1_h[kk * 64]);
      #pragma unroll
      for (int mt = 0; mt < 4; ++mt) a0[mt] = mfma16(bc(Ah[mt]), b0, a0[mt]);
      #pragma unroll
      for (int mt = 0; mt < 4; ++mt) a1[mt] = mfma16(bc(Ah[mt]), b1, a1[mt]);
      #pragma unroll
      for (int mt = 0; mt < 4; ++mt) a0[mt] = mfma16(bc(Al[mt]), b0, a0[mt]);
      #pragma unroll
      for (int mt = 0; mt < 4; ++mt) a1[mt] = mfma16(bc(Al[mt]), b1, a1[mt]);
    }
    #pragma unroll
    for (int mt = 0; mt < 4; ++mt)
      #pragma unroll
      for (int i = 0; i < 4; ++i) {
        T0n[mt][i] = s[mt][i] * a0[mt][i];
        T1n[mt][i] = s[mt][i] * a1[mt][i];
      }
    if (l < 6) {
      pack16h_lds(T0n, B0_h);
      pack16h_lds(T1n, B1_h);
    }
  }

  // ---- output: J_{jo} = T_j . Wout[:,o];  u = [J10, -J00, J01, J11] ----
  float J00 = 0.f, J01 = 0.f, J10 = 0.f, J11 = 0.f;
  #pragma unroll
  for (int mt = 0; mt < 4; ++mt) {
    f32x4 wa = *(const f32x4*)&Wout[(16 * mt + fb) * 2];      // feats f0,f1: (W0,W1,W0,W1)
    f32x4 wb = *(const f32x4*)&Wout[(16 * mt + fb) * 2 + 4];  // feats f2,f3
    J00 = fmaf(T0n[mt][0], wa[0], fmaf(T0n[mt][1], wa[2], fmaf(T0n[mt][2], wb[0], fmaf(T0n[mt][3], wb[2], J00))));
    J01 = fmaf(T0n[mt][0], wa[1], fmaf(T0n[mt][1], wa[3], fmaf(T0n[mt][2], wb[1], fmaf(T0n[mt][3], wb[3], J01))));
    J10 = fmaf(T1n[mt][0], wa[0], fmaf(T1n[mt][1], wa[2], fmaf(T1n[mt][2], wb[0], fmaf(T1n[mt][3], wb[2], J10))));
    J11 = fmaf(T1n[mt][0], wa[1], fmaf(T1n[mt][1], wa[3], fmaf(T1n[mt][2], wb[1], fmaf(T1n[mt][3], wb[3], J11))));
  }
  J00 = xreduce(J00); J01 = xreduce(J01); J10 = xreduce(J10); J11 = xreduce(J11);
  float val = (g == 0) ? J10 : (g == 1) ? -J00 : (g == 2) ? J01 : J11;
  out[(p0 + p) * 4 + g] = val;
}

extern "C" void kernel_launch(void* const* d_in, const int* in_sizes, int n_in,
                              void* d_out, int out_size, void* d_ws, size_t ws_size,
                              hipStream_t stream) {
  const float* x    = (const float*)d_in[0];
  const float* Win  = (const float*)d_in[1];
  const float* bin  = (const float*)d_in[2];
  const float* Ws   = (const float*)d_in[3];
  const float* bs   = (const float*)d_in[4];
  const float* Wout = (const float*)d_in[5];
  float* out = (float*)d_out;

  uint4* whi = (uint4*)d_ws;
  uint4* wlo = whi + 56 * 64;

  int N = in_sizes[0] / 3;      // 524288

  prep_kernel<<<56, 64, 0, stream>>>(Ws, whi, wlo);
  velprevec_kernel<<<N / 64, 256, 0, stream>>>(x, Win, bin, bs, Wout, whi, wlo, out);
}